// Round 10
// baseline (380.534 us; speedup 1.0000x reference)
//
#include <hip/hip_runtime.h>
#include <cmath>
#include <cstdint>

typedef __bf16 bf16;
typedef __bf16 bf16x8 __attribute__((ext_vector_type(8)));
typedef __bf16 bf16x4 __attribute__((ext_vector_type(4)));
typedef float f32x4 __attribute__((ext_vector_type(4)));
typedef _Float16 f16;
typedef _Float16 f16x4 __attribute__((ext_vector_type(4)));

#define CEXP 0.1803368852f   // 0.125 / ln(2)

// ---------------- async global->LDS (width 16) ----------------
__device__ __forceinline__ void async_ld16(const void* g, void* l) {
  __builtin_amdgcn_global_load_lds(
      (__attribute__((address_space(1))) void*)(uintptr_t)g,
      (__attribute__((address_space(3))) void*)l, 16, 0, 0);
}

// ---------------- fused fp32 -> bf16 cast of all 7 tensors ----------------
__global__ __launch_bounds__(256) void cast_all(
    const float* __restrict__ x,  const float* __restrict__ wq, const float* __restrict__ wk,
    const float* __restrict__ wv, const float* __restrict__ wo, const float* __restrict__ w1,
    const float* __restrict__ w2,
    bf16* xb, bf16* wqb, bf16* wkb, bf16* wvb, bf16* wob, bf16* w1b, bf16* w2b)
{
  int i = blockIdx.x * 256 + threadIdx.x;
  const int M1 = 1 << 20, Q = 1 << 18;
  const float* src; bf16* dst; int off;
  if      (i < M1)            { src = x;  dst = xb;  off = i; }
  else if (i < M1 + Q)        { src = wq; dst = wqb; off = i - M1; }
  else if (i < M1 + 2 * Q)    { src = wk; dst = wkb; off = i - M1 - Q; }
  else if (i < M1 + 3 * Q)    { src = wv; dst = wvb; off = i - M1 - 2 * Q; }
  else if (i < M1 + 4 * Q)    { src = wo; dst = wob; off = i - M1 - 3 * Q; }
  else if (i < 3 * M1)        { src = w1; dst = w1b; off = i - M1 - 4 * Q; }
  else                        { src = w2; dst = w2b; off = i - 3 * M1; }
  float4 v = ((const float4*)src)[off];
  bf16x4 o; o[0]=(bf16)v.x; o[1]=(bf16)v.y; o[2]=(bf16)v.z; o[3]=(bf16)v.w;
  ((bf16x4*)dst)[off] = o;
}

// ======== QKV GEMM (2-phase 128x128) with fused V-transpose epilogue (V stored as f16) ========
// z in {0,1,2} -> (Wq,bq)->Qb, (Wk,bk)->Kb, (Wv,bv)->Vt DIRECTLY (transposed via LDS).
// Vt layout: Vt[(b*1024 + h*64 + d)*1024 + s], dtype f16 (consumed only by attn PV).
__global__ __launch_bounds__(256) void gemm_qkv(
    const bf16* __restrict__ A, const bf16* __restrict__ Bq, const bf16* __restrict__ Bk,
    const bf16* __restrict__ Bv, const float* __restrict__ bq, const float* __restrict__ bk,
    const float* __restrict__ bv, bf16* Oq, bf16* Ok, f16* Vt, int N, int K)
{
  // staging: As(2x128x32) + Bs(2x128x32) = 16384 elems; transpose tile 128x136 = 17408 elems
  __shared__ __align__(16) bf16 Sb[17408];   // 34816 B
  bf16* As = Sb;
  bf16* Bs = Sb + 8192;
  const bf16* Bm  = blockIdx.z == 0 ? Bq : (blockIdx.z == 1 ? Bk : Bv);
  const float* bi = blockIdx.z == 0 ? bq : (blockIdx.z == 1 ? bk : bv);

  const int tid  = threadIdx.x;
  const int wave = tid >> 6, lane = tid & 63;
  const int lr = lane & 15, lq = lane >> 4;
  const int bm = blockIdx.x * 128, bn = blockIdx.y * 128;
  const int wm = (wave >> 1) * 64, wn = (wave & 1) * 64;
  const int srow = lane >> 2, scol = (lane & 3) * 8;

  const f32x4 fz = {0.f, 0.f, 0.f, 0.f};
  f32x4 acc[4][4];
#pragma unroll
  for (int i = 0; i < 4; i++)
#pragma unroll
    for (int j = 0; j < 4; j++) acc[i][j] = fz;

  auto issue = [&](int k0, int buf) {
    bf16* Ad = As + buf * (128 * 32);
    bf16* Bd = Bs + buf * (128 * 32);
#pragma unroll
    for (int cc = 0; cc < 2; ++cc) {
      int c = wave * 2 + cc;
      async_ld16(A + (size_t)(bm + c * 16 + srow) * K + k0 + scol, Ad + c * 512);
    }
#pragma unroll
    for (int cc = 0; cc < 2; ++cc) {
      int c = wave * 2 + cc;
      async_ld16(Bm + (size_t)(bn + c * 16 + srow) * K + k0 + scol, Bd + c * 512);
    }
  };

  const int nit = K >> 5;
  issue(0, 0);
  for (int i = 0; i < nit; i++) {
    __syncthreads();                          // drains loads into buf i&1
    if (i + 1 < nit) issue((i + 1) * 32, (i + 1) & 1);
    const bf16* Ab = As + (i & 1) * (128 * 32);
    const bf16* Bb = Bs + (i & 1) * (128 * 32);
    bf16x8 af[4], bfr[4];
#pragma unroll
    for (int mi = 0; mi < 4; mi++) af[mi]  = *(const bf16x8*)(Ab + (wm + mi*16 + lr)*32 + lq*8);
#pragma unroll
    for (int ni = 0; ni < 4; ni++) bfr[ni] = *(const bf16x8*)(Bb + (wn + ni*16 + lr)*32 + lq*8);
#pragma unroll
    for (int mi = 0; mi < 4; mi++)
#pragma unroll
      for (int ni = 0; ni < 4; ni++)
        acc[mi][ni] = __builtin_amdgcn_mfma_f32_16x16x32_bf16(af[mi], bfr[ni], acc[mi][ni], 0, 0, 0);
  }

  if (blockIdx.z != 2) {
    // natural epilogue: O[m][n] = acc + bias
    bf16* O = blockIdx.z == 0 ? Oq : Ok;
#pragma unroll
    for (int ni = 0; ni < 4; ni++) {
      int n = bn + wn + ni*16 + lr;
      float bv2 = bi[n];
#pragma unroll
      for (int mi = 0; mi < 4; mi++)
#pragma unroll
        for (int r = 0; r < 4; r++) {
          int m = bm + wm + mi*16 + lq*4 + r;
          O[(size_t)m * N + n] = (bf16)(acc[mi][ni][r] + bv2);
        }
    }
  } else {
    // V: transpose through LDS (pitch 136, f16 bits in 2B slots), write Vt coalesced
    __syncthreads();                          // all staging reads complete
#pragma unroll
    for (int ni = 0; ni < 4; ni++) {
      int nl = wn + ni*16 + lr;
      float bv2 = bi[bn + nl];
#pragma unroll
      for (int mi = 0; mi < 4; mi++)
#pragma unroll
        for (int r = 0; r < 4; r++) {
          int ml = wm + mi*16 + lq*4 + r;
          *(f16*)&Sb[nl * 136 + ml] = (f16)(acc[mi][ni][r] + bv2);
        }
    }
    __syncthreads();
    const int rl = tid >> 1, ch = (tid & 1) * 64;   // 2 threads per Vt row
    f16* dst = Vt + ((size_t)((bm >> 10) * 1024 + bn + rl)) * 1024 + (bm & 1023) + ch;
    const bf16* src = Sb + rl * 136 + ch;
#pragma unroll
    for (int j = 0; j < 8; j++)
      *(uint4*)(dst + j * 8) = *(const uint4*)(src + j * 8);
  }
}

// ======== 256x256 deep-pipelined GEMM core (FFN1) ========
__device__ __forceinline__ void gemm256_core(
    const bf16* __restrict__ A, const bf16* __restrict__ Bm,
    const float* __restrict__ bias, bf16* __restrict__ outB, float* __restrict__ outF,
    int N, int kld, int kbeg, int kend, int relu, bf16* As, bf16* Bs)
{
  const int tid  = threadIdx.x;
  const int wave = tid >> 6, lane = tid & 63;
  const int lr = lane & 15, lq = lane >> 4;
  const int bm = blockIdx.x * 256, bn = blockIdx.y * 256;
  const int wm = (wave >> 2) * 128, wn = (wave & 3) * 64;   // 2M x 4N waves, 128x64 each

  const f32x4 fz = {0.f, 0.f, 0.f, 0.f};
  f32x4 acc[8][4];
#pragma unroll
  for (int i = 0; i < 8; ++i)
#pragma unroll
    for (int j = 0; j < 4; ++j) acc[i][j] = fz;

  int srow[4], scol[4];
#pragma unroll
  for (int L = 0; L < 4; ++L) {
    int cidx = L * 512 + wave * 64 + lane;
    srow[L] = cidx >> 3;
    scol[L] = ((cidx & 7) ^ (srow[L] & 7)) * 8;     // pre-swizzled global col-chunk
  }

  auto issue = [&](int kt, int buf) {
    const int k0 = kbeg + kt * 64;
#pragma unroll
    for (int L = 0; L < 4; ++L)
      async_ld16(A + (size_t)(bm + srow[L]) * kld + k0 + scol[L],
                 As + buf * (256 * 64) + (L * 512 + wave * 64) * 8);
#pragma unroll
    for (int L = 0; L < 4; ++L)
      async_ld16(Bm + (size_t)(bn + srow[L]) * kld + k0 + scol[L],
                 Bs + buf * (256 * 64) + (L * 512 + wave * 64) * 8);
  };

  const int NT = (kend - kbeg) >> 6;           // BK = 64; requires NT >= 2
  issue(0, 0);
  issue(1, 1);
  asm volatile("s_waitcnt vmcnt(8)" ::: "memory");
  __builtin_amdgcn_sched_barrier(0);
  __builtin_amdgcn_s_barrier();

  for (int t = 0; t < NT; ++t) {
    const bf16* Ab = As + (t & 1) * (256 * 64);
    const bf16* Bb = Bs + (t & 1) * (256 * 64);
#pragma unroll
    for (int mh = 0; mh < 2; ++mh) {
      bf16x8 af[4][2];
#pragma unroll
      for (int mi = 0; mi < 4; ++mi) {
        int row = wm + mh * 64 + mi * 16 + lr;
#pragma unroll
        for (int ks = 0; ks < 2; ++ks)
          af[mi][ks] = *(const bf16x8*)(Ab + row * 64 + (((ks * 4 + lq) ^ (lr & 7)) * 8));
      }
#pragma unroll
      for (int nh = 0; nh < 2; ++nh) {
        bf16x8 bfr[2][2];
#pragma unroll
        for (int ni = 0; ni < 2; ++ni) {
          int row = wn + nh * 32 + ni * 16 + lr;
#pragma unroll
          for (int ks = 0; ks < 2; ++ks)
            bfr[ni][ks] = *(const bf16x8*)(Bb + row * 64 + (((ks * 4 + lq) ^ (lr & 7)) * 8));
        }
        __builtin_amdgcn_s_setprio(1);
#pragma unroll
        for (int mi = 0; mi < 4; ++mi)
#pragma unroll
          for (int ni = 0; ni < 2; ++ni)
#pragma unroll
            for (int ks = 0; ks < 2; ++ks)
              acc[mh * 4 + mi][nh * 2 + ni] = __builtin_amdgcn_mfma_f32_16x16x32_bf16(
                  af[mi][ks], bfr[ni][ks], acc[mh * 4 + mi][nh * 2 + ni], 0, 0, 0);
        __builtin_amdgcn_s_setprio(0);
      }
    }
    if (t + 1 == NT) break;
    asm volatile("s_waitcnt lgkmcnt(0)" ::: "memory");
    __builtin_amdgcn_sched_barrier(0);
    __builtin_amdgcn_s_barrier();
    if (t + 2 < NT) {
      issue(t + 2, t & 1);
      asm volatile("s_waitcnt vmcnt(8)" ::: "memory");
    } else {
      asm volatile("s_waitcnt vmcnt(0)" ::: "memory");
    }
    __builtin_amdgcn_sched_barrier(0);
    __builtin_amdgcn_s_barrier();
  }

#pragma unroll
  for (int mi8 = 0; mi8 < 8; ++mi8) {
#pragma unroll
    for (int ni4 = 0; ni4 < 4; ++ni4) {
      int n = bn + wn + ni4 * 16 + lr;
      float bv = bias ? bias[n] : 0.0f;
#pragma unroll
      for (int r = 0; r < 4; ++r) {
        int m = bm + wm + mi8 * 16 + lq * 4 + r;
        size_t idx = (size_t)m * N + n;
        float v = acc[mi8][ni4][r] + bv;
        if (relu) v = fmaxf(v, 0.0f);
        if (outF) outF[idx] = v;
        else      outB[idx] = (bf16)v;
      }
    }
  }
}

__global__ __launch_bounds__(512) void gemm256(
    const bf16* __restrict__ A, const bf16* __restrict__ Bm,
    const float* __restrict__ bias, bf16* __restrict__ outB,
    int N, int K, int relu)
{
  __shared__ __align__(16) bf16 As[2 * 256 * 64];   // 64 KiB
  __shared__ __align__(16) bf16 Bs[2 * 256 * 64];   // 64 KiB
  gemm256_core(A, Bm, bias, outB, nullptr, N, K, 0, K, relu, As, Bs);
}

// ======== 256x128 deep-pipelined split-K GEMM ========
__device__ __forceinline__ void gemm256x128_core(
    const bf16* __restrict__ A, const bf16* __restrict__ Bm, float* __restrict__ outF,
    int N, int kld, int kbeg, int kend, bf16* As, bf16* Bs)
{
  const int tid  = threadIdx.x;
  const int wave = tid >> 6, lane = tid & 63;
  const int lr = lane & 15, lq = lane >> 4;
  const int bm = blockIdx.x * 256, bn = blockIdx.y * 128;
  const int wm = (wave >> 1) * 64, wn = (wave & 1) * 64;    // 4M x 2N waves, 64x64 each

  const f32x4 fz = {0.f, 0.f, 0.f, 0.f};
  f32x4 acc[4][4];
#pragma unroll
  for (int i = 0; i < 4; ++i)
#pragma unroll
    for (int j = 0; j < 4; ++j) acc[i][j] = fz;

  int srowA[4], scolA[4], srowB[2], scolB[2];
#pragma unroll
  for (int L = 0; L < 4; ++L) {
    int cidx = L * 512 + wave * 64 + lane;
    srowA[L] = cidx >> 3;
    scolA[L] = ((cidx & 7) ^ (srowA[L] & 7)) * 8;
  }
#pragma unroll
  for (int L = 0; L < 2; ++L) {
    int cidx = L * 512 + wave * 64 + lane;
    srowB[L] = cidx >> 3;
    scolB[L] = ((cidx & 7) ^ (srowB[L] & 7)) * 8;
  }

  auto issue = [&](int kt, int buf) {
    const int k0 = kbeg + kt * 64;
#pragma unroll
    for (int L = 0; L < 4; ++L)
      async_ld16(A + (size_t)(bm + srowA[L]) * kld + k0 + scolA[L],
                 As + buf * (256 * 64) + (L * 512 + wave * 64) * 8);
#pragma unroll
    for (int L = 0; L < 2; ++L)
      async_ld16(Bm + (size_t)(bn + srowB[L]) * kld + k0 + scolB[L],
                 Bs + buf * (128 * 64) + (L * 512 + wave * 64) * 8);
  };

  const int NT = (kend - kbeg) >> 6;           // BK = 64; requires NT >= 2
  issue(0, 0);
  issue(1, 1);
  asm volatile("s_waitcnt vmcnt(6)" ::: "memory");
  __builtin_amdgcn_sched_barrier(0);
  __builtin_amdgcn_s_barrier();

  for (int t = 0; t < NT; ++t) {
    const bf16* Ab = As + (t & 1) * (256 * 64);
    const bf16* Bb = Bs + (t & 1) * (128 * 64);
    bf16x8 af[4][2], bfr[4][2];
#pragma unroll
    for (int mi = 0; mi < 4; ++mi) {
      int row = wm + mi * 16 + lr;
#pragma unroll
      for (int ks = 0; ks < 2; ++ks)
        af[mi][ks] = *(const bf16x8*)(Ab + row * 64 + (((ks * 4 + lq) ^ (lr & 7)) * 8));
    }
#pragma unroll
    for (int ni = 0; ni < 4; ++ni) {
      int row = wn + ni * 16 + lr;
#pragma unroll
      for (int ks = 0; ks < 2; ++ks)
        bfr[ni][ks] = *(const bf16x8*)(Bb + row * 64 + (((ks * 4 + lq) ^ (lr & 7)) * 8));
    }
    __builtin_amdgcn_s_setprio(1);
#pragma unroll
    for (int mi = 0; mi < 4; ++mi)
#pragma unroll
      for (int ni = 0; ni < 4; ++ni)
#pragma unroll
        for (int ks = 0; ks < 2; ++ks)
          acc[mi][ni] = __builtin_amdgcn_mfma_f32_16x16x32_bf16(
              af[mi][ks], bfr[ni][ks], acc[mi][ni], 0, 0, 0);
    __builtin_amdgcn_s_setprio(0);

    if (t + 1 == NT) break;
    asm volatile("s_waitcnt lgkmcnt(0)" ::: "memory");
    __builtin_amdgcn_sched_barrier(0);
    __builtin_amdgcn_s_barrier();
    if (t + 2 < NT) {
      issue(t + 2, t & 1);
      asm volatile("s_waitcnt vmcnt(6)" ::: "memory");
    } else {
      asm volatile("s_waitcnt vmcnt(0)" ::: "memory");
    }
    __builtin_amdgcn_sched_barrier(0);
    __builtin_amdgcn_s_barrier();
  }

#pragma unroll
  for (int mi = 0; mi < 4; ++mi) {
#pragma unroll
    for (int ni = 0; ni < 4; ++ni) {
      int n = bn + wn + ni * 16 + lr;
#pragma unroll
      for (int r = 0; r < 4; ++r) {
        int m = bm + wm + mi * 16 + lq * 4 + r;
        outF[(size_t)m * N + n] = acc[mi][ni][r];
      }
    }
  }
}

__global__ __launch_bounds__(512) void gemm256x128_splitk(
    const bf16* __restrict__ A, const bf16* __restrict__ Bm,
    float* p0, float* p1, int N, int kld, int kchunk)
{
  __shared__ __align__(16) bf16 As[2 * 256 * 64];   // 64 KiB
  __shared__ __align__(16) bf16 Bs[2 * 128 * 64];   // 32 KiB
  const int z = blockIdx.z;
  float* part = z == 0 ? p0 : p1;
  gemm256x128_core(A, Bm, part, N, kld, z * kchunk, (z + 1) * kchunk, As, Bs);
}

// ---------------- flash attention v9: barrier-free main loop, in-register P ----------------
// Swapped QK^T output (lane: q=lane&15, k=lq*4+r) IS the A-operand of mfma_f32_16x16x16f16.
// Each wave computes PV over its own 16-k slice with V f16x4 frags loaded straight from
// global Vt (f16). Zero barriers per tile; one cross-wave O reduction per block.
#define S_LEN 1024
#define ROWSTR 1024

__global__ __launch_bounds__(256) void attn_kernel(
    const bf16* __restrict__ Qg, const bf16* __restrict__ Kg, const f16* __restrict__ Vt,
    const float* __restrict__ Wrel, bf16* __restrict__ Og)
{
  __shared__ __align__(16) bf16 hist[64][136];   // 17408 B
  __shared__ __align__(16) bf16 rel_s[64][132];  // 16896 B; epilogue Bred + lbuf/hbuf overlay
  __shared__ __align__(16) bf16 ovl[8704];       // 17408 B: Wst / Ared / Wr_t overlay
  bf16* Wst  = ovl;                  // preamble [128][64] packed
  bf16* Wr_t = ovl;                  // epilogue [64][136]
  float* Ared = (float*)ovl;         // epilogue O-reduction buf A [64][65] f32 (16640 B)
  float* Bred = (float*)rel_s;       // epilogue O-reduction buf B [64][65] f32
  float* lbuf = (float*)rel_s;       // final [4][64]
  float* hbuf = lbuf + 256;

  const int tid = threadIdx.x;
  const int wave = tid >> 6, lane = tid & 63;
  const int lr = lane & 15, lq = lane >> 4;
  const int qblk = 15 - blockIdx.y;              // LPT: y=0 => T=16 blocks first
  const int bh = blockIdx.x;
  const int b = bh >> 4, h = bh & 15;
  const int q0 = qblk * 64;
  const int T = qblk + 1;
  const int nearStart = (T > 3) ? T - 3 : 0;
  const size_t rowbase = (size_t)b * S_LEN * ROWSTR + h * 64;
  const f32x4 fz = {0.f, 0.f, 0.f, 0.f};

  // ---- preamble: stage Wrel[128..255] packed [t][d] pitch 64; zero hist ----
  for (int e = tid; e < 2048; e += 256) {
    float4 v = ((const float4*)(Wrel + 8192))[e];
    bf16x4 o; o[0]=(bf16)v.x; o[1]=(bf16)v.y; o[2]=(bf16)v.z; o[3]=(bf16)v.w;
    ((bf16x4*)Wst)[e] = o;
  }
  {
    uint4 z4 = {0u, 0u, 0u, 0u};
    for (int e = tid; e < 1088; e += 256) ((uint4*)hist)[e] = z4;
  }

  // Q fragments: all 64 q-rows per wave
  bf16x8 qf[4][2];
#pragma unroll
  for (int qt = 0; qt < 4; qt++)
#pragma unroll
    for (int c = 0; c < 2; c++)
      qf[qt][c] = *(const bf16x8*)(Qg + rowbase + (size_t)(q0 + qt*16 + lr) * ROWSTR + c*32 + lq*8);

  // Wrel[256] broadcast A-frag
  bf16x8 wb[2];
#pragma unroll
  for (int c = 0; c < 2; c++)
#pragma unroll
    for (int j = 0; j < 8; j++)
      wb[c][j] = (bf16)Wrel[(size_t)256 * 64 + c*32 + lq*8 + j];

  __syncthreads();

  // rel^T[t][q] = Wrel[t+128].Q[q], pre-scaled by CEXP (for exp2)
#pragma unroll
  for (int tt = 0; tt < 2; ++tt)
#pragma unroll
    for (int qt = 0; qt < 4; ++qt) {
      f32x4 a = fz;
#pragma unroll
      for (int c = 0; c < 2; c++) {
        bf16x8 wf = *(const bf16x8*)(Wst + (wave*32 + tt*16 + lr) * 64 + c*32 + lq*8);
        a = __builtin_amdgcn_mfma_f32_16x16x32_bf16(wf, qf[qt][c], a, 0, 0, 0);
      }
      bf16x4 pk; pk[0]=(bf16)(a[0]*CEXP); pk[1]=(bf16)(a[1]*CEXP);
                 pk[2]=(bf16)(a[2]*CEXP); pk[3]=(bf16)(a[3]*CEXP);
      *(bf16x4*)(&rel_s[qt*16 + lr][wave*32 + tt*16 + lq*4]) = pk;
    }
  {  // t = 128 column
    f32x4 a = fz;
#pragma unroll
    for (int c = 0; c < 2; c++)
      a = __builtin_amdgcn_mfma_f32_16x16x32_bf16(wb[c], qf[wave][c], a, 0, 0, 0);
    if (lq == 0) rel_s[wave*16 + lr][128] = (bf16)(a[0]*CEXP);
  }
  __syncthreads();

  float relc[4];
#pragma unroll
  for (int qt = 0; qt < 4; qt++) relc[qt] = (float)rel_s[qt*16 + lr][128];

  float l_p[4] = {0.f,0.f,0.f,0.f}, h_p[4] = {0.f,0.f,0.f,0.f};
  f32x4 acc_n[4][4];   // [qt][dt]: O_partial[q=qt*16+lq*4+r][d=dt*16+lr] over wave's k-slice
#pragma unroll
  for (int i = 0; i < 4; i++)
#pragma unroll
    for (int j = 0; j < 4; j++) acc_n[i][j] = fz;

  // V fragment addressing: B-operand of 16x16x16 -> V[k0+16*wave+lq*4+j][dt*16+lr]
  const f16* vrow = Vt + (size_t)(bh * 64) * 1024;
  int vdoff[4];
#pragma unroll
  for (int dt = 0; dt < 4; dt++) vdoff[dt] = (dt*16 + lr) * 1024 + 16*wave + lq*4;

  const int krow = 16 * wave + lr;
  bf16x8 kf0, kf1, kn0, kn1;
  f16x4 vf[4], vn[4];
  {
    const bf16* kp = Kg + rowbase + (size_t)krow * ROWSTR + lq*8;
    kf0 = *(const bf16x8*)kp; kf1 = *(const bf16x8*)(kp + 32);
#pragma unroll
    for (int dt = 0; dt < 4; dt++) vf[dt] = *(const f16x4*)(vrow + vdoff[dt]);
  }

  for (int kt = 0; kt < T; ++kt) {
    const int k0 = kt * 64;

    // S^T[k][q]: lane holds P[q=lr][k=16*wave+lq*4+r] per qt
    f32x4 sc[4];
#pragma unroll
    for (int qt = 0; qt < 4; qt++) {
      sc[qt] = __builtin_amdgcn_mfma_f32_16x16x32_bf16(kf0, qf[qt][0], fz, 0, 0, 0);
      sc[qt] = __builtin_amdgcn_mfma_f32_16x16x32_bf16(kf1, qf[qt][1], sc[qt], 0, 0, 0);
    }
    // prefetch next tile (K frags + V frags)
    if (kt + 1 < T) {
      const bf16* kp = Kg + rowbase + (size_t)(k0 + 64 + krow) * ROWSTR + lq*8;
      kn0 = *(const bf16x8*)kp; kn1 = *(const bf16x8*)(kp + 32);
#pragma unroll
      for (int dt = 0; dt < 4; dt++) vn[dt] = *(const f16x4*)(vrow + vdoff[dt] + k0 + 64);
    }

    // softmax (m=0, exp2 domain)
    float pw[4][4];
    if (kt < nearStart) {
#pragma unroll
      for (int qt = 0; qt < 4; qt++) {
#pragma unroll
        for (int r = 0; r < 4; r++) pw[qt][r] = exp2f(fmaf(sc[qt][r], CEXP, relc[qt]));
        float s4 = pw[qt][0] + pw[qt][1] + pw[qt][2] + pw[qt][3];
        l_p[qt] += s4; h_p[qt] += s4;
      }
    } else {
#pragma unroll
      for (int qt = 0; qt < 4; qt++) {
        int qg = q0 + qt*16 + lr;
#pragma unroll
        for (int r = 0; r < 4; r++) {
          int kg = k0 + 16*wave + lq*4 + r;
          float p = 0.0f;
          if (kg <= qg) {
            int t = qg - kg; int tc = t > 128 ? 128 : t;
            p = exp2f(fmaf(sc[qt][r], CEXP, (float)rel_s[qt*16 + lr][tc]));
            l_p[qt] += p;
            if (t >= 128) h_p[qt] += p;
            else          hist[qt*16 + lr][t] = (bf16)p;
          }
          pw[qt][r] = p;
        }
      }
    }

    // PV in-register: A = P frag (direct from QK^T layout), B = V frag (global f16)
#pragma unroll
    for (int qt = 0; qt < 4; qt++) {
      f16x4 pa; pa[0]=(f16)pw[qt][0]; pa[1]=(f16)pw[qt][1];
                pa[2]=(f16)pw[qt][2]; pa[3]=(f16)pw[qt][3];
#pragma unroll
      for (int dt = 0; dt < 4; dt++)
        acc_n[qt][dt] = __builtin_amdgcn_mfma_f32_16x16x16f16(pa, vf[dt], acc_n[qt][dt], 0, 0, 0);
    }
    kf0 = kn0; kf1 = kn1;
#pragma unroll
    for (int dt = 0; dt < 4; dt++) vf[dt] = vn[dt];
  }

  // ---- cross-wave O reduction (once per block) ----
  __syncthreads();   // all waves done (last rel_s reads complete)
  {
    float* buf = (wave & 2) ? Bred : Ared;
    if (!(wave & 1)) {           // waves 0,2 store
#pragma unroll
      for (int qt = 0; qt < 4; qt++)
#pragma unroll
        for (int dt = 0; dt < 4; dt++)
#pragma unroll
          for (int r = 0; r < 4; r++)
            buf[(qt*16 + lq*4 + r) * 65 + dt*16 + lr] = acc_n[qt][dt][r];
    }
    __syncthreads();
    if (wave & 1) {              // waves 1,3 accumulate
#pragma unroll
      for (int qt = 0; qt < 4; qt++)
#pragma unroll
        for (int dt = 0; dt < 4; dt++)
#pragma unroll
          for (int r = 0; r < 4; r++)
            buf[(qt*16 + lq*4 + r) * 65 + dt*16 + lr] += acc_n[qt][dt][r];
    }
    __syncthreads();
  }
  // recover per-wave q-slice layout: q = wave*16 + lq*4 + r, d = dt*16 + lr
  f32x4 acc_o[4];
#pragma unroll
  for (int dt = 0; dt < 4; dt++)
#pragma unroll
    for (int r = 0; r < 4; r++) {
      int q = wave*16 + lq*4 + r;
      acc_o[dt][r] = Ared[q*65 + dt*16 + lr] + Bred[q*65 + dt*16 + lr];
    }
  __syncthreads();   // Ared/Bred dead -> ovl becomes Wr_t, rel_s becomes lbuf/hbuf

  // ---- epilogue ----
#pragma unroll
  for (int qt = 0; qt < 4; qt++) {
    l_p[qt] += __shfl_xor(l_p[qt], 16); l_p[qt] += __shfl_xor(l_p[qt], 32);
    h_p[qt] += __shfl_xor(h_p[qt], 16); h_p[qt] += __shfl_xor(h_p[qt], 32);
  }
  if (lq == 0) {
#pragma unroll
    for (int qt = 0; qt < 4; qt++) {
      lbuf[wave*64 + qt*16 + lr] = l_p[qt];
      hbuf[wave*64 + qt*16 + lr] = h_p[qt];
    }
  }
  for (int e = tid; e < 64 * 128; e += 256) {   // Wr^T[d][t], pitch 136
    int d = e >> 7, t = e & 127;
    Wr_t[d * 136 + t] = (bf16)Wrel[(size_t)(128 + t) * 64 + d];
  }
  __syncthreads();
#pragma unroll
  for (int c = 0; c < 4; c++) {                 // out += hist @ Wrel[t<128]
    bf16x8 hf = *(const bf16x8*)&hist[wave*16 + lr][c*32 + lq*8];
#pragma unroll
    for (int dt = 0; dt < 4; dt++) {
      bf16x8 wf = *(const bf16x8*)(Wr_t + (dt*16 + lr) * 136 + c*32 + lq*8);
      acc_o[dt] = __builtin_amdgcn_mfma_f32_16x16x32_bf16(hf, wf, acc_o[dt], 0, 0, 0);
    }
  }
  float l4[4], h4[4];
#pragma unroll
  for (int r = 0; r < 4; r++) {
    int q = wave*16 + lq*4 + r;
    l4[r] = lbuf[q] + lbuf[64+q] + lbuf[128+q] + lbuf[192+q];
    h4[r] = hbuf[q] + hbuf[64+q] + hbuf[128+q] + hbuf[192+q];
  }
#pragma unroll
  for (int dt = 0; dt < 4; dt++) {
    float wv = Wrel[(size_t)256 * 64 + dt*16 + lr];
#pragma unroll
    for (int r = 0; r < 4; r++) acc_o[dt][r] += h4[r] * wv;
  }
#pragma unroll
  for (int dt = 0; dt < 4; dt++)
#pragma unroll
    for (int r = 0; r < 4; r++) {
      int qg = q0 + wave*16 + lq*4 + r;
      Og[rowbase + (size_t)qg * ROWSTR + dt*16 + lr] = (bf16)(acc_o[dt][r] / l4[r]);
    }
}

// ------- fused split-K reduce (2-4 partials) + bias + residual + LayerNorm -------
__global__ __launch_bounds__(256) void ln_fuse(
    const float* __restrict__ pA, const float* __restrict__ pB,
    const float* __restrict__ pC, const float* __restrict__ pD,
    const float* __restrict__ bias,
    const float* __restrict__ residF, const bf16* __restrict__ residB,
    const float* __restrict__ alpha, const float* __restrict__ beta,
    float* __restrict__ outF, bf16* __restrict__ outB)
{
  const int row = blockIdx.x, tid = threadIdx.x;
  const int lane = tid & 63, wave = tid >> 6;
  const size_t base = (size_t)row * 1024;
  float4 v = ((const float4*)(pA + base))[tid];
  float4 v2 = ((const float4*)(pB + base))[tid];
  v.x += v2.x; v.y += v2.y; v.z += v2.z; v.w += v2.w;
  if (pC) {
    float4 v3 = ((const float4*)(pC + base))[tid];
    v.x += v3.x; v.y += v3.y; v.z += v3.z; v.w += v3.w;
  }
  if (pD) {
    float4 v4 = ((const float4*)(pD + base))[tid];
    v.x += v4.x; v.y += v4.y; v.z += v4.z; v.w += v4.w;
  }
  float4 bv = ((const float4*)bias)[tid];
  v.x += bv.x; v.y += bv.y; v.z += bv.z; v.w += bv.w;
  if (residF) {
    float4 rv = ((const float4*)(residF + base))[tid];
    v.x += rv.x; v.y += rv.y; v.z += rv.z; v.w += rv.w;
  }
  if (residB) {
    bf16x4 rv = ((const bf16x4*)(residB + base))[tid];
    v.x += (float)rv[0]; v.y += (float)rv[1]; v.z += (float)rv[2]; v.w += (float)rv[3];
  }
  float s  = v.x + v.y + v.z + v.w;
  float ss = v.x*v.x + v.y*v.y + v.z*v.z + v.w*v.w;
#pragma unroll
  for (int off = 32; off; off >>= 1) { s += __shfl_down(s, off); ss += __shfl_down(ss, off); }
  __shared__ float rs[4], rss[4];
  if (lane == 0) { rs[wave] = s; rss[wave] = ss; }
  __syncthreads();
  s  = rs[0] + rs[1] + rs[2] + rs[3];
  ss = rss[0] + rss[1] + rss[2] + rss[3];
  float mean = s * (1.0f / 1024.0f);
  float var  = ss * (1.0f / 1024.0f) - mean * mean;
  float inv  = 1.0f / (sqrtf(fmaxf(var, 0.0f)) + 1e-5f);
  float4 a = ((const float4*)alpha)[tid];
  float4 bb = ((const float4*)beta)[tid];
  float o0 = a.x * (v.x - mean) * inv + bb.x;
  float o1 = a.y * (v.y - mean) * inv + bb.y;
  float o2 = a.z * (v.z - mean) * inv + bb.z;
  float o3 = a.w * (v.w - mean) * inv + bb.w;
  if (outF) { float4 o = {o0, o1, o2, o3}; ((float4*)(outF + base))[tid] = o; }
  if (outB) { bf16x4 o; o[0]=(bf16)o0; o[1]=(bf16)o1; o[2]=(bf16)o2; o[3]=(bf16)o3;
              ((bf16x4*)(outB + base))[tid] = o; }
}

// ---------------- launcher ----------------
extern "C" void kernel_launch(void* const* d_in, const int* in_sizes, int n_in,
                              void* d_out, int out_size, void* d_ws, size_t ws_size,
                              hipStream_t stream) {
  (void)in_sizes; (void)n_in; (void)out_size; (void)ws_size;
  const int D = 1024, DFF = 4096;

  const float* x    = (const float*)d_in[0];
  const float* Wq   = (const float*)d_in[2];
  const float* bq   = (const float*)d_in[3];
  const float* Wk   = (const float*)d_in[4];
  const float* bk   = (const float*)d_in[5];
  const float* Wv   = (const float*)d_in[6];
  const float* bv   = (const float*)d_in[7];
  const float* Wo   = (const float*)d_in[8];
  const float* bo   = (const float*)d_in[9];
  const float* Wrel = (const float*)d_in[10];
  const float* g1   = (const float*)d_in[11];
  const float* be1  = (const float*)d_in[12];
  const float* g2   = (const float*)d_in[13];
  const float* be2  = (const float*)d_in[14];
  const float* W1   = (const float*)d_in[15];
  const float* b1   = (const float*)d_in[16];
  const float* W2   = (const float*)d_in[17];
  const float* b2   = (const float*)d_in[18];

  char* ws = (char*)d_ws;
  const size_t MB = 1024 * 1024;
  bf16*  xb   = (bf16*)(ws + 0);        // 8 MB; reused as h_bf16 after LN1
  bf16*  Wqb  = (bf16*)(ws + 8  * MB);
  bf16*  Wkb  = (bf16*)(ws + 10 * MB);
  bf16*  Wvb  = (bf16*)(ws + 12 * MB);
  bf16*  Wob  = (bf16*)(ws + 14 * MB);
  bf16*  W1b  = (bf16*)(ws + 16 * MB);  // 8 MB
  bf16*  W2b  = (bf16*)(ws + 24 * MB);  // 8 MB
  bf16*  Qb   = (bf16*)(ws + 32 * MB);  // 8 MB
  bf16*  Kb   = (bf16*)(ws + 40 * MB);
  f16*   Vt   = (f16*)(ws + 56 * MB);   // V^T [(b*16+h)*64+d][1024], f16, from gemm_qkv z=2
  bf16*  AOb  = (bf16*)(ws + 48 * MB);  // attention out
  float* part = (float*)(ws + 64 * MB); // 2 x 16 MB fp32 split-K partials
  bf16*  f1   = Qb;                     // 32 MB overlay (Qb..Vt dead by FFN1)
  bf16*  hb   = xb;
  float* p0 = part;
  float* p1 = part + (size_t)4096 * 1024;

  cast_all<<<16384, 256, 0, stream>>>(x, Wq, Wk, Wv, Wo, W1, W2,
                                      xb, Wqb, Wkb, Wvb, Wob, W1b, W2b);

  // QKV: 2-phase 128x128; z=2 writes V TRANSPOSED as f16 directly
  gemm_qkv<<<dim3(32, 8, 3), 256, 0, stream>>>(xb, Wqb, Wkb, Wvb, bq, bk, bv, Qb, Kb, Vt, D, D);
  attn_kernel<<<dim3(64, 16), 256, 0, stream>>>(Qb, Kb, Vt, Wrel, AOb);
  // AO projection: 256x128 split-K z=2 -> 256 blocks, NT=8
  gemm256x128_splitk<<<dim3(16, 8, 2), 512, 0, stream>>>(AOb, Wob, p0, p1, D, D, 512);
  ln_fuse<<<4096, 256, 0, stream>>>(p0, p1, nullptr, nullptr,
                                    bo, x, nullptr, g1, be1, nullptr, hb);
  gemm256<<<dim3(16, 16), 512, 0, stream>>>(hb, W1b, b1, f1, DFF, D, 1);
  // FFN2: 256x128 split-K z=2 -> 256 blocks, NT=32
  gemm256x128_splitk<<<dim3(16, 8, 2), 512, 0, stream>>>(f1, W2b, p0, p1, D, DFF, 2048);
  ln_fuse<<<4096, 256, 0, stream>>>(p0, p1, nullptr, nullptr,
                                    b2, nullptr, hb, g2, be2, (float*)d_out, nullptr);
}

// Round 11
// 372.692 us; speedup vs baseline: 1.0210x; 1.0210x over previous
//
#include <hip/hip_runtime.h>
#include <cmath>
#include <cstdint>

typedef __bf16 bf16;
typedef __bf16 bf16x8 __attribute__((ext_vector_type(8)));
typedef __bf16 bf16x4 __attribute__((ext_vector_type(4)));
typedef float f32x4 __attribute__((ext_vector_type(4)));

#define CEXP 0.1803368852f   // 0.125 / ln(2)

// ---------------- async global->LDS (width 16) ----------------
__device__ __forceinline__ void async_ld16(const void* g, void* l) {
  __builtin_amdgcn_global_load_lds(
      (__attribute__((address_space(1))) void*)(uintptr_t)g,
      (__attribute__((address_space(3))) void*)l, 16, 0, 0);
}

// ---------------- fused fp32 -> bf16 cast of all 7 tensors ----------------
__global__ __launch_bounds__(256) void cast_all(
    const float* __restrict__ x,  const float* __restrict__ wq, const float* __restrict__ wk,
    const float* __restrict__ wv, const float* __restrict__ wo, const float* __restrict__ w1,
    const float* __restrict__ w2,
    bf16* xb, bf16* wqb, bf16* wkb, bf16* wvb, bf16* wob, bf16* w1b, bf16* w2b)
{
  int i = blockIdx.x * 256 + threadIdx.x;
  const int M1 = 1 << 20, Q = 1 << 18;
  const float* src; bf16* dst; int off;
  if      (i < M1)            { src = x;  dst = xb;  off = i; }
  else if (i < M1 + Q)        { src = wq; dst = wqb; off = i - M1; }
  else if (i < M1 + 2 * Q)    { src = wk; dst = wkb; off = i - M1 - Q; }
  else if (i < M1 + 3 * Q)    { src = wv; dst = wvb; off = i - M1 - 2 * Q; }
  else if (i < M1 + 4 * Q)    { src = wo; dst = wob; off = i - M1 - 3 * Q; }
  else if (i < 3 * M1)        { src = w1; dst = w1b; off = i - M1 - 4 * Q; }
  else                        { src = w2; dst = w2b; off = i - 3 * M1; }
  float4 v = ((const float4*)src)[off];
  bf16x4 o; o[0]=(bf16)v.x; o[1]=(bf16)v.y; o[2]=(bf16)v.z; o[3]=(bf16)v.w;
  ((bf16x4*)dst)[off] = o;
}

// ------- GEMM core, LDS double-buffered, ONE barrier per BK=32 iteration -------
template<int BM>
__device__ __forceinline__ void gemm_core(
    const bf16* __restrict__ A, const bf16* __restrict__ Bm, const float* __restrict__ bias,
    float* __restrict__ outF, bf16* __restrict__ outB,
    const float* __restrict__ residF, const bf16* __restrict__ residB,
    int N, int kld, int kbeg, int kend, int relu, bf16* As, bf16* Bs)
{
  constexpr int MI = BM / 32;
  const int tid  = threadIdx.x;
  const int wave = tid >> 6, lane = tid & 63;
  const int lr = lane & 15, lq = lane >> 4;
  const int bm = blockIdx.x * BM, bn = blockIdx.y * 128;
  const int wm = (wave >> 1) * (BM / 2), wn = (wave & 1) * 64;
  const int srow = lane >> 2, scol = (lane & 3) * 8;

  const f32x4 fz = {0.f, 0.f, 0.f, 0.f};
  f32x4 acc[MI][4];
#pragma unroll
  for (int i = 0; i < MI; i++)
#pragma unroll
    for (int j = 0; j < 4; j++) acc[i][j] = fz;

  auto issue = [&](int k0, int buf) {
    bf16* Ad = As + buf * (BM * 32);
    bf16* Bd = Bs + buf * (128 * 32);
    if (BM == 128) {
#pragma unroll
      for (int cc = 0; cc < 2; ++cc) {
        int c = wave * 2 + cc;
        async_ld16(A + (size_t)(bm + c * 16 + srow) * kld + k0 + scol, Ad + c * 512);
      }
    } else {
      async_ld16(A + (size_t)(bm + wave * 16 + srow) * kld + k0 + scol, Ad + wave * 512);
    }
#pragma unroll
    for (int cc = 0; cc < 2; ++cc) {
      int c = wave * 2 + cc;
      async_ld16(Bm + (size_t)(bn + c * 16 + srow) * kld + k0 + scol, Bd + c * 512);
    }
  };

  const int nit = (kend - kbeg) >> 5;
  issue(kbeg, 0);
  for (int i = 0; i < nit; i++) {
    __syncthreads();                          // drains loads into buf i&1
    if (i + 1 < nit) issue(kbeg + (i + 1) * 32, (i + 1) & 1);   // overlap with MFMA below
    const bf16* Ab = As + (i & 1) * (BM * 32);
    const bf16* Bb = Bs + (i & 1) * (128 * 32);
    bf16x8 af[MI], bfr[4];
#pragma unroll
    for (int mi = 0; mi < MI; mi++) af[mi]  = *(const bf16x8*)(Ab + (wm + mi*16 + lr)*32 + lq*8);
#pragma unroll
    for (int ni = 0; ni < 4; ni++) bfr[ni] = *(const bf16x8*)(Bb + (wn + ni*16 + lr)*32 + lq*8);
#pragma unroll
    for (int mi = 0; mi < MI; mi++)
#pragma unroll
      for (int ni = 0; ni < 4; ni++)
        acc[mi][ni] = __builtin_amdgcn_mfma_f32_16x16x32_bf16(af[mi], bfr[ni], acc[mi][ni], 0, 0, 0);
  }

#pragma unroll
  for (int ni = 0; ni < 4; ni++) {
    int n = bn + wn + ni*16 + lr;
    float bv = bias ? bias[n] : 0.0f;
#pragma unroll
    for (int mi = 0; mi < MI; mi++) {
#pragma unroll
      for (int r = 0; r < 4; r++) {
        int m = bm + wm + mi*16 + lq*4 + r;
        size_t idx = (size_t)m * N + n;
        float v = acc[mi][ni][r] + bv;
        if (relu) v = fmaxf(v, 0.0f);
        if (residF) v += residF[idx];
        if (residB) v += (float)residB[idx];
        if (outF) outF[idx] = v;
        else      outB[idx] = (bf16)v;
      }
    }
  }
}

__global__ __launch_bounds__(256) void gemm_qkv(
    const bf16* A, const bf16* Bq, const bf16* Bk, const bf16* Bv,
    const float* bq, const float* bk, const float* bv,
    bf16* Oq, bf16* Ok, bf16* Ov, int N, int K)
{
  __shared__ bf16 As[2 * 128 * 32];
  __shared__ bf16 Bs[2 * 128 * 32];
  const bf16* Bm  = blockIdx.z == 0 ? Bq : (blockIdx.z == 1 ? Bk : Bv);
  const float* bi = blockIdx.z == 0 ? bq : (blockIdx.z == 1 ? bk : bv);
  bf16* O         = blockIdx.z == 0 ? Oq : (blockIdx.z == 1 ? Ok : Ov);
  gemm_core<128>(A, Bm, bi, nullptr, O, nullptr, nullptr, N, K, 0, K, 0, As, Bs);
}

// ======== 256x256 deep-pipelined GEMM core (FFN1) ========
__device__ __forceinline__ void gemm256_core(
    const bf16* __restrict__ A, const bf16* __restrict__ Bm,
    const float* __restrict__ bias, bf16* __restrict__ outB, float* __restrict__ outF,
    int N, int kld, int kbeg, int kend, int relu, bf16* As, bf16* Bs)
{
  const int tid  = threadIdx.x;
  const int wave = tid >> 6, lane = tid & 63;
  const int lr = lane & 15, lq = lane >> 4;
  const int bm = blockIdx.x * 256, bn = blockIdx.y * 256;
  const int wm = (wave >> 2) * 128, wn = (wave & 3) * 64;   // 2M x 4N waves, 128x64 each

  const f32x4 fz = {0.f, 0.f, 0.f, 0.f};
  f32x4 acc[8][4];
#pragma unroll
  for (int i = 0; i < 8; ++i)
#pragma unroll
    for (int j = 0; j < 4; ++j) acc[i][j] = fz;

  int srow[4], scol[4];
#pragma unroll
  for (int L = 0; L < 4; ++L) {
    int cidx = L * 512 + wave * 64 + lane;
    srow[L] = cidx >> 3;
    scol[L] = ((cidx & 7) ^ (srow[L] & 7)) * 8;     // pre-swizzled global col-chunk
  }

  auto issue = [&](int kt, int buf) {
    const int k0 = kbeg + kt * 64;
#pragma unroll
    for (int L = 0; L < 4; ++L)
      async_ld16(A + (size_t)(bm + srow[L]) * kld + k0 + scol[L],
                 As + buf * (256 * 64) + (L * 512 + wave * 64) * 8);
#pragma unroll
    for (int L = 0; L < 4; ++L)
      async_ld16(Bm + (size_t)(bn + srow[L]) * kld + k0 + scol[L],
                 Bs + buf * (256 * 64) + (L * 512 + wave * 64) * 8);
  };

  const int NT = (kend - kbeg) >> 6;           // BK = 64; requires NT >= 2
  issue(0, 0);
  issue(1, 1);
  asm volatile("s_waitcnt vmcnt(8)" ::: "memory");
  __builtin_amdgcn_sched_barrier(0);
  __builtin_amdgcn_s_barrier();

  for (int t = 0; t < NT; ++t) {
    const bf16* Ab = As + (t & 1) * (256 * 64);
    const bf16* Bb = Bs + (t & 1) * (256 * 64);
#pragma unroll
    for (int mh = 0; mh < 2; ++mh) {
      bf16x8 af[4][2];
#pragma unroll
      for (int mi = 0; mi < 4; ++mi) {
        int row = wm + mh * 64 + mi * 16 + lr;
#pragma unroll
        for (int ks = 0; ks < 2; ++ks)
          af[mi][ks] = *(const bf16x8*)(Ab + row * 64 + (((ks * 4 + lq) ^ (lr & 7)) * 8));
      }
#pragma unroll
      for (int nh = 0; nh < 2; ++nh) {
        bf16x8 bfr[2][2];
#pragma unroll
        for (int ni = 0; ni < 2; ++ni) {
          int row = wn + nh * 32 + ni * 16 + lr;
#pragma unroll
          for (int ks = 0; ks < 2; ++ks)
            bfr[ni][ks] = *(const bf16x8*)(Bb + row * 64 + (((ks * 4 + lq) ^ (lr & 7)) * 8));
        }
        __builtin_amdgcn_s_setprio(1);
#pragma unroll
        for (int mi = 0; mi < 4; ++mi)
#pragma unroll
          for (int ni = 0; ni < 2; ++ni)
#pragma unroll
            for (int ks = 0; ks < 2; ++ks)
              acc[mh * 4 + mi][nh * 2 + ni] = __builtin_amdgcn_mfma_f32_16x16x32_bf16(
                  af[mi][ks], bfr[ni][ks], acc[mh * 4 + mi][nh * 2 + ni], 0, 0, 0);
        __builtin_amdgcn_s_setprio(0);
      }
    }
    if (t + 1 == NT) break;
    asm volatile("s_waitcnt lgkmcnt(0)" ::: "memory");
    __builtin_amdgcn_sched_barrier(0);
    __builtin_amdgcn_s_barrier();
    if (t + 2 < NT) {
      issue(t + 2, t & 1);
      asm volatile("s_waitcnt vmcnt(8)" ::: "memory");
    } else {
      asm volatile("s_waitcnt vmcnt(0)" ::: "memory");
    }
    __builtin_amdgcn_sched_barrier(0);
    __builtin_amdgcn_s_barrier();
  }

#pragma unroll
  for (int mi8 = 0; mi8 < 8; ++mi8) {
#pragma unroll
    for (int ni4 = 0; ni4 < 4; ++ni4) {
      int n = bn + wn + ni4 * 16 + lr;
      float bv = bias ? bias[n] : 0.0f;
#pragma unroll
      for (int r = 0; r < 4; ++r) {
        int m = bm + wm + mi8 * 16 + lq * 4 + r;
        size_t idx = (size_t)m * N + n;
        float v = acc[mi8][ni4][r] + bv;
        if (relu) v = fmaxf(v, 0.0f);
        if (outF) outF[idx] = v;
        else      outB[idx] = (bf16)v;
      }
    }
  }
}

__global__ __launch_bounds__(512) void gemm256(
    const bf16* __restrict__ A, const bf16* __restrict__ Bm,
    const float* __restrict__ bias, bf16* __restrict__ outB,
    int N, int K, int relu)
{
  __shared__ __align__(16) bf16 As[2 * 256 * 64];   // 64 KiB
  __shared__ __align__(16) bf16 Bs[2 * 256 * 64];   // 64 KiB
  gemm256_core(A, Bm, bias, outB, nullptr, N, K, 0, K, relu, As, Bs);
}

// ======== 256x128 deep-pipelined split-K GEMM ========
__device__ __forceinline__ void gemm256x128_core(
    const bf16* __restrict__ A, const bf16* __restrict__ Bm, float* __restrict__ outF,
    int N, int kld, int kbeg, int kend, bf16* As, bf16* Bs)
{
  const int tid  = threadIdx.x;
  const int wave = tid >> 6, lane = tid & 63;
  const int lr = lane & 15, lq = lane >> 4;
  const int bm = blockIdx.x * 256, bn = blockIdx.y * 128;
  const int wm = (wave >> 1) * 64, wn = (wave & 1) * 64;    // 4M x 2N waves, 64x64 each

  const f32x4 fz = {0.f, 0.f, 0.f, 0.f};
  f32x4 acc[4][4];
#pragma unroll
  for (int i = 0; i < 4; ++i)
#pragma unroll
    for (int j = 0; j < 4; ++j) acc[i][j] = fz;

  int srowA[4], scolA[4], srowB[2], scolB[2];
#pragma unroll
  for (int L = 0; L < 4; ++L) {
    int cidx = L * 512 + wave * 64 + lane;
    srowA[L] = cidx >> 3;
    scolA[L] = ((cidx & 7) ^ (srowA[L] & 7)) * 8;
  }
#pragma unroll
  for (int L = 0; L < 2; ++L) {
    int cidx = L * 512 + wave * 64 + lane;
    srowB[L] = cidx >> 3;
    scolB[L] = ((cidx & 7) ^ (srowB[L] & 7)) * 8;
  }

  auto issue = [&](int kt, int buf) {
    const int k0 = kbeg + kt * 64;
#pragma unroll
    for (int L = 0; L < 4; ++L)
      async_ld16(A + (size_t)(bm + srowA[L]) * kld + k0 + scolA[L],
                 As + buf * (256 * 64) + (L * 512 + wave * 64) * 8);
#pragma unroll
    for (int L = 0; L < 2; ++L)
      async_ld16(Bm + (size_t)(bn + srowB[L]) * kld + k0 + scolB[L],
                 Bs + buf * (128 * 64) + (L * 512 + wave * 64) * 8);
  };

  const int NT = (kend - kbeg) >> 6;           // BK = 64; requires NT >= 2
  issue(0, 0);
  issue(1, 1);
  asm volatile("s_waitcnt vmcnt(6)" ::: "memory");
  __builtin_amdgcn_sched_barrier(0);
  __builtin_amdgcn_s_barrier();

  for (int t = 0; t < NT; ++t) {
    const bf16* Ab = As + (t & 1) * (256 * 64);
    const bf16* Bb = Bs + (t & 1) * (128 * 64);
    bf16x8 af[4][2], bfr[4][2];
#pragma unroll
    for (int mi = 0; mi < 4; ++mi) {
      int row = wm + mi * 16 + lr;
#pragma unroll
      for (int ks = 0; ks < 2; ++ks)
        af[mi][ks] = *(const bf16x8*)(Ab + row * 64 + (((ks * 4 + lq) ^ (lr & 7)) * 8));
    }
#pragma unroll
    for (int ni = 0; ni < 4; ++ni) {
      int row = wn + ni * 16 + lr;
#pragma unroll
      for (int ks = 0; ks < 2; ++ks)
        bfr[ni][ks] = *(const bf16x8*)(Bb + row * 64 + (((ks * 4 + lq) ^ (lr & 7)) * 8));
    }
    __builtin_amdgcn_s_setprio(1);
#pragma unroll
    for (int mi = 0; mi < 4; ++mi)
#pragma unroll
      for (int ni = 0; ni < 4; ++ni)
#pragma unroll
        for (int ks = 0; ks < 2; ++ks)
          acc[mi][ni] = __builtin_amdgcn_mfma_f32_16x16x32_bf16(
              af[mi][ks], bfr[ni][ks], acc[mi][ni], 0, 0, 0);
    __builtin_amdgcn_s_setprio(0);

    if (t + 1 == NT) break;
    asm volatile("s_waitcnt lgkmcnt(0)" ::: "memory");
    __builtin_amdgcn_sched_barrier(0);
    __builtin_amdgcn_s_barrier();
    if (t + 2 < NT) {
      issue(t + 2, t & 1);
      asm volatile("s_waitcnt vmcnt(6)" ::: "memory");
    } else {
      asm volatile("s_waitcnt vmcnt(0)" ::: "memory");
    }
    __builtin_amdgcn_sched_barrier(0);
    __builtin_amdgcn_s_barrier();
  }

#pragma unroll
  for (int mi = 0; mi < 4; ++mi) {
#pragma unroll
    for (int ni = 0; ni < 4; ++ni) {
      int n = bn + wn + ni * 16 + lr;
#pragma unroll
      for (int r = 0; r < 4; ++r) {
        int m = bm + wm + mi * 16 + lq * 4 + r;
        outF[(size_t)m * N + n] = acc[mi][ni][r];
      }
    }
  }
}

__global__ __launch_bounds__(512) void gemm256x128_splitk(
    const bf16* __restrict__ A, const bf16* __restrict__ Bm,
    float* p0, float* p1, int N, int kld, int kchunk)
{
  __shared__ __align__(16) bf16 As[2 * 256 * 64];   // 64 KiB
  __shared__ __align__(16) bf16 Bs[2 * 128 * 64];   // 32 KiB
  const int z = blockIdx.z;
  float* part = z == 0 ? p0 : p1;
  gemm256x128_core(A, Bm, part, N, kld, z * kchunk, (z + 1) * kchunk, As, Bs);
}

// ---------------- V transpose: V[b,s,h,d] -> Vt[(b*16+h)*64+d][s] ----------------
__global__ __launch_bounds__(256) void transpose_v(const bf16* __restrict__ V, bf16* __restrict__ Vt) {
  __shared__ bf16 t[64][72];
  const int tid = threadIdx.x;
  const int sblk = blockIdx.x;          // 16 s-tiles of 64
  const int bh = blockIdx.y;            // 64
  const int b = bh >> 4, h = bh & 15;
  const int sr = tid >> 2, dc = (tid & 3) * 16;
  const bf16* src = V + ((size_t)(b * 1024 + sblk * 64 + sr)) * 1024 + h * 64 + dc;
  bf16x8 r0 = *(const bf16x8*)src;
  bf16x8 r1 = *(const bf16x8*)(src + 8);
  *(bf16x8*)(&t[sr][dc]) = r0;
  *(bf16x8*)(&t[sr][dc + 8]) = r1;
  __syncthreads();
  const int dr = tid >> 2, sc = (tid & 3) * 16;
  bf16 o[16];
#pragma unroll
  for (int j = 0; j < 16; j++) o[j] = t[sc + j][dr];
  bf16* dst = Vt + ((size_t)(bh * 64 + dr)) * 1024 + sblk * 64 + sc;
  *(bf16x8*)dst = *(bf16x8*)&o[0];
  *(bf16x8*)(dst + 8) = *(bf16x8*)&o[8];
}

// ---------------- flash attention v7: LPT dispatch (bh fastest, long q-blocks first) ----------------
#define S_LEN 1024
#define ROWSTR 1024

__global__ __launch_bounds__(256) void attn_kernel(
    const bf16* __restrict__ Qg, const bf16* __restrict__ Kg, const bf16* __restrict__ Vt,
    const float* __restrict__ Wrel, bf16* __restrict__ Og)
{
  __shared__ __align__(16) bf16 hist[64][136];   // 17408 B
  __shared__ __align__(16) bf16 rel_s[64][132];  // 16896 B; epilogue lbuf/hbuf overlay
  __shared__ __align__(16) bf16 ovl[8704];       // 17408 B: V_T(4096) + P(4608)
  bf16* V_T  = ovl;                  // swizzled 16B chunks: chunk(d,jx)=d*8+jx, j=jx^(d&7)
  bf16* Pb   = ovl + 4096;           // [64][72]
  bf16* Wst  = ovl;                  // preamble [128][64] packed
  bf16* Wr_t = ovl;                  // epilogue [64][136]
  float* lbuf = (float*)rel_s;       // epilogue [4][64]
  float* hbuf = lbuf + 256;

  const int tid = threadIdx.x;
  const int wave = tid >> 6, lane = tid & 63;
  const int lr = lane & 15, lq = lane >> 4;
  const int qblk = 15 - blockIdx.y;              // LPT: y=0 => T=16 blocks first
  const int bh = blockIdx.x;
  const int b = bh >> 4, h = bh & 15;
  const int q0 = qblk * 64;
  const int T = qblk + 1;
  const int nearStart = (T > 3) ? T - 3 : 0;
  const size_t rowbase = (size_t)b * S_LEN * ROWSTR + h * 64;
  const size_t vtbase = (size_t)(bh * 64) * 1024;
  const f32x4 fz = {0.f, 0.f, 0.f, 0.f};

  // ---- preamble: stage Wrel[128..255] packed [t][d] pitch 64 (float4-vectorized); zero hist ----
  for (int e = tid; e < 2048; e += 256) {
    float4 v = ((const float4*)(Wrel + 8192))[e];
    bf16x4 o; o[0]=(bf16)v.x; o[1]=(bf16)v.y; o[2]=(bf16)v.z; o[3]=(bf16)v.w;
    ((bf16x4*)Wst)[e] = o;
  }
  {
    uint4 z4 = {0u, 0u, 0u, 0u};
    for (int e = tid; e < 1088; e += 256) ((uint4*)hist)[e] = z4;
  }

  // Q fragments: all 64 q-rows per wave
  bf16x8 qf[4][2];
#pragma unroll
  for (int qt = 0; qt < 4; qt++)
#pragma unroll
    for (int c = 0; c < 2; c++)
      qf[qt][c] = *(const bf16x8*)(Qg + rowbase + (size_t)(q0 + qt*16 + lr) * ROWSTR + c*32 + lq*8);

  // Wrel[256] broadcast A-frag
  bf16x8 wb[2];
#pragma unroll
  for (int c = 0; c < 2; c++)
#pragma unroll
    for (int j = 0; j < 8; j++)
      wb[c][j] = (bf16)Wrel[(size_t)256 * 64 + c*32 + lq*8 + j];

  __syncthreads();

  // rel^T[t][q] = Wrel[t+128].Q[q], pre-scaled by CEXP (for exp2)
#pragma unroll
  for (int tt = 0; tt < 2; ++tt)
#pragma unroll
    for (int qt = 0; qt < 4; ++qt) {
      f32x4 a = fz;
#pragma unroll
      for (int c = 0; c < 2; c++) {
        bf16x8 wf = *(const bf16x8*)(Wst + (wave*32 + tt*16 + lr) * 64 + c*32 + lq*8);
        a = __builtin_amdgcn_mfma_f32_16x16x32_bf16(wf, qf[qt][c], a, 0, 0, 0);
      }
      bf16x4 pk; pk[0]=(bf16)(a[0]*CEXP); pk[1]=(bf16)(a[1]*CEXP);
                 pk[2]=(bf16)(a[2]*CEXP); pk[3]=(bf16)(a[3]*CEXP);
      *(bf16x4*)(&rel_s[qt*16 + lr][wave*32 + tt*16 + lq*4]) = pk;
    }
  {  // t = 128 column
    f32x4 a = fz;
#pragma unroll
    for (int c = 0; c < 2; c++)
      a = __builtin_amdgcn_mfma_f32_16x16x32_bf16(wb[c], qf[wave][c], a, 0, 0, 0);
    if (lq == 0) rel_s[wave*16 + lr][128] = (bf16)(a[0]*CEXP);
  }
  __syncthreads();

  float relc[4];
#pragma unroll
  for (int qt = 0; qt < 4; qt++) relc[qt] = (float)rel_s[qt*16 + lr][128];

  float l_p[4] = {0.f,0.f,0.f,0.f}, h_p[4] = {0.f,0.f,0.f,0.f};
  f32x4 acc_o[4];
#pragma unroll
  for (int dt = 0; dt < 4; dt++) acc_o[dt] = fz;

  // V^T staging addressing (swizzled): thread owns chunks tid and tid+256
  const int vd1 = tid >> 3;
  const int vj  = (tid & 7) ^ (vd1 & 7);
  const int krow = 16 * wave + lr;

  uint4 va, vb, va2, vb2;
  bf16x8 kf0, kf1, kn0, kn1;
  {
    const bf16* vp = Vt + vtbase + (size_t)vd1 * 1024 + vj * 8;
    va = *(const uint4*)vp; vb = *(const uint4*)(vp + 32 * 1024);
    const bf16* kp = Kg + rowbase + (size_t)krow * ROWSTR + lq*8;
    kf0 = *(const bf16x8*)kp; kf1 = *(const bf16x8*)(kp + 32);
  }

  for (int kt = 0; kt < T; ++kt) {
    const int k0 = kt * 64;

    // S^T[k][q]
    f32x4 sc[4];
#pragma unroll
    for (int qt = 0; qt < 4; qt++) {
      sc[qt] = __builtin_amdgcn_mfma_f32_16x16x32_bf16(kf0, qf[qt][0], fz, 0, 0, 0);
      sc[qt] = __builtin_amdgcn_mfma_f32_16x16x32_bf16(kf1, qf[qt][1], sc[qt], 0, 0, 0);
    }
    // prefetch next tile (K frags + V^T chunks)
    if (kt + 1 < T) {
      const bf16* vp = Vt + vtbase + (size_t)vd1 * 1024 + k0 + 64 + vj * 8;
      va2 = *(const uint4*)vp; vb2 = *(const uint4*)(vp + 32 * 1024);
      const bf16* kp = Kg + rowbase + (size_t)(k0 + 64 + krow) * ROWSTR + lq*8;
      kn0 = *(const bf16x8*)kp; kn1 = *(const bf16x8*)(kp + 32);
    }

    // softmax (m=0, exp2 domain)
    float pw[4][4];
    if (kt < nearStart) {
#pragma unroll
      for (int qt = 0; qt < 4; qt++) {
#pragma unroll
        for (int r = 0; r < 4; r++) pw[qt][r] = exp2f(fmaf(sc[qt][r], CEXP, relc[qt]));
        float s4 = pw[qt][0] + pw[qt][1] + pw[qt][2] + pw[qt][3];
        l_p[qt] += s4; h_p[qt] += s4;
      }
    } else {
#pragma unroll
      for (int qt = 0; qt < 4; qt++) {
        int qg = q0 + qt*16 + lr;
#pragma unroll
        for (int r = 0; r < 4; r++) {
          int kg = k0 + 16*wave + lq*4 + r;
          float p = 0.0f;
          if (kg <= qg) {
            int t = qg - kg; int tc = t > 128 ? 128 : t;
            p = exp2f(fmaf(sc[qt][r], CEXP, (float)rel_s[qt*16 + lr][tc]));
            l_p[qt] += p;
            if (t >= 128) h_p[qt] += p;
            else          hist[qt*16 + lr][t] = (bf16)p;
          }
          pw[qt][r] = p;
        }
      }
    }

    __syncthreads();   // prev PV reads of V_T/P complete
    // stage V^T (swizzled b128 writes, conflict-free)
    *(uint4*)(V_T + tid * 8) = va;
    *(uint4*)(V_T + (tid + 256) * 8) = vb;
    // write P[q][k]: 4 consecutive k per lane -> b64
#pragma unroll
    for (int qt = 0; qt < 4; qt++) {
      bf16x4 pk; pk[0]=(bf16)pw[qt][0]; pk[1]=(bf16)pw[qt][1];
                 pk[2]=(bf16)pw[qt][2]; pk[3]=(bf16)pw[qt][3];
      *(bf16x4*)(Pb + (qt*16 + lr) * 72 + 16*wave + lq*4) = pk;
    }
    __syncthreads();   // staging + P visible

    // PV: O[q][d] (q-split per wave)
#pragma unroll
    for (int c = 0; c < 2; c++) {
      bf16x8 pf = *(const bf16x8*)(Pb + (16*wave + lr) * 72 + c*32 + lq*8);
#pragma unroll
      for (int dt = 0; dt < 4; dt++) {
        int vd = dt*16 + lr;
        int jx = (c*4 + lq) ^ (vd & 7);
        bf16x8 vf = *(const bf16x8*)(V_T + ((vd << 3) + jx) * 8);
        acc_o[dt] = __builtin_amdgcn_mfma_f32_16x16x32_bf16(pf, vf, acc_o[dt], 0, 0, 0);
      }
    }
    kf0 = kn0; kf1 = kn1; va = va2; vb = vb2;
  }

  // ---- epilogue ----
#pragma unroll
  for (int qt = 0; qt < 4; qt++) {
    l_p[qt] += __shfl_xor(l_p[qt], 16); l_p[qt] += __shfl_xor(l_p[qt], 32);
    h_p[qt] += __shfl_xor(h_p[qt], 16); h_p[qt] += __shfl_xor(h_p[qt], 32);
  }
  __syncthreads();
  if (lq == 0) {
#pragma unroll
    for (int qt = 0; qt < 4; qt++) {
      lbuf[wave*64 + qt*16 + lr] = l_p[qt];
      hbuf[wave*64 + qt*16 + lr] = h_p[qt];
    }
  }
  for (int e = tid; e < 64 * 128; e += 256) {   // Wr^T[d][t], pitch 136
    int d = e >> 7, t = e & 127;
    Wr_t[d * 136 + t] = (bf16)Wrel[(size_t)(128 + t) * 64 + d];
  }
  __syncthreads();
#pragma unroll
  for (int c = 0; c < 4; c++) {                 // out += hist @ Wrel[t<128]
    bf16x8 hf = *(const bf16x8*)&hist[wave*16 + lr][c*32 + lq*8];
#pragma unroll
    for (int dt = 0; dt < 4; dt++) {
      bf16x8 wf = *(const bf16x8*)(Wr_t + (dt*16 + lr) * 136 + c*32 + lq*8);
      acc_o[dt] = __builtin_amdgcn_mfma_f32_16x16x32_bf16(hf, wf, acc_o[dt], 0, 0, 0);
    }
  }
  float l4[4], h4[4];
#pragma unroll
  for (int r = 0; r < 4; r++) {
    int q = wave*16 + lq*4 + r;
    l4[r] = lbuf[q] + lbuf[64+q] + lbuf[128+q] + lbuf[192+q];
    h4[r] = hbuf[q] + hbuf[64+q] + hbuf[128+q] + hbuf[192+q];
  }
#pragma unroll
  for (int dt = 0; dt < 4; dt++) {
    float wv = Wrel[(size_t)256 * 64 + dt*16 + lr];
#pragma unroll
    for (int r = 0; r < 4; r++) acc_o[dt][r] += h4[r] * wv;
  }
#pragma unroll
  for (int dt = 0; dt < 4; dt++)
#pragma unroll
    for (int r = 0; r < 4; r++) {
      int qg = q0 + wave*16 + lq*4 + r;
      Og[rowbase + (size_t)qg * ROWSTR + dt*16 + lr] = (bf16)(acc_o[dt][r] / l4[r]);
    }
}

// ------- fused split-K reduce (2-4 partials) + bias + residual + LayerNorm -------
__global__ __launch_bounds__(256) void ln_fuse(
    const float* __restrict__ pA, const float* __restrict__ pB,
    const float* __restrict__ pC, const float* __restrict__ pD,
    const float* __restrict__ bias,
    const float* __restrict__ residF, const bf16* __restrict__ residB,
    const float* __restrict__ alpha, const float* __restrict__ beta,
    float* __restrict__ outF, bf16* __restrict__ outB)
{
  const int row = blockIdx.x, tid = threadIdx.x;
  const int lane = tid & 63, wave = tid >> 6;
  const size_t base = (size_t)row * 1024;
  float4 v = ((const float4*)(pA + base))[tid];
  float4 v2 = ((const float4*)(pB + base))[tid];
  v.x += v2.x; v.y += v2.y; v.z += v2.z; v.w += v2.w;
  if (pC) {
    float4 v3 = ((const float4*)(pC + base))[tid];
    v.x += v3.x; v.y += v3.y; v.z += v3.z; v.w += v3.w;
  }
  if (pD) {
    float4 v4 = ((const float4*)(pD + base))[tid];
    v.x += v4.x; v.y += v4.y; v.z += v4.z; v.w += v4.w;
  }
  float4 bv = ((const float4*)bias)[tid];
  v.x += bv.x; v.y += bv.y; v.z += bv.z; v.w += bv.w;
  if (residF) {
    float4 rv = ((const float4*)(residF + base))[tid];
    v.x += rv.x; v.y += rv.y; v.z += rv.z; v.w += rv.w;
  }
  if (residB) {
    bf16x4 rv = ((const bf16x4*)(residB + base))[tid];
    v.x += (float)rv[0]; v.y += (float)rv[1]; v.z += (float)rv[2]; v.w += (float)rv[3];
  }
  float s  = v.x + v.y + v.z + v.w;
  float ss = v.x*v.x + v.y*v.y + v.z*v.z + v.w*v.w;
#pragma unroll
  for (int off = 32; off; off >>= 1) { s += __shfl_down(s, off); ss += __shfl_down(ss, off); }
  __shared__ float rs[4], rss[4];
  if (lane == 0) { rs[wave] = s; rss[wave] = ss; }
  __syncthreads();
  s  = rs[0] + rs[1] + rs[2] + rs[3];
  ss = rss[0] + rss[1] + rss[2] + rss[3];
  float mean = s * (1.0f / 1024.0f);
  float var  = ss * (1.0f / 1024.0f) - mean * mean;
  float inv  = 1.0f / (sqrtf(fmaxf(var, 0.0f)) + 1e-5f);
  float4 a = ((const float4*)alpha)[tid];
  float4 bb = ((const float4*)beta)[tid];
  float o0 = a.x * (v.x - mean) * inv + bb.x;
  float o1 = a.y * (v.y - mean) * inv + bb.y;
  float o2 = a.z * (v.z - mean) * inv + bb.z;
  float o3 = a.w * (v.w - mean) * inv + bb.w;
  if (outF) { float4 o = {o0, o1, o2, o3}; ((float4*)(outF + base))[tid] = o; }
  if (outB) { bf16x4 o; o[0]=(bf16)o0; o[1]=(bf16)o1; o[2]=(bf16)o2; o[3]=(bf16)o3;
              ((bf16x4*)(outB + base))[tid] = o; }
}

// ---------------- launcher ----------------
extern "C" void kernel_launch(void* const* d_in, const int* in_sizes, int n_in,
                              void* d_out, int out_size, void* d_ws, size_t ws_size,
                              hipStream_t stream) {
  (void)in_sizes; (void)n_in; (void)out_size; (void)ws_size;
  const int D = 1024, DFF = 4096;

  const float* x    = (const float*)d_in[0];
  const float* Wq   = (const float*)d_in[2];
  const float* bq   = (const float*)d_in[3];
  const float* Wk   = (const float*)d_in[4];
  const float* bk   = (const float*)d_in[5];
  const float* Wv   = (const float*)d_in[6];
  const float* bv   = (const float*)d_in[7];
  const float* Wo   = (const float*)d_in[8];
  const float* bo   = (const float*)d_in[9];
  const float* Wrel = (const float*)d_in[10];
  const float* g1   = (const float*)d_in[11];
  const float* be1  = (const float*)d_in[12];
  const float* g2   = (const float*)d_in[13];
  const float* be2  = (const float*)d_in[14];
  const float* W1   = (const float*)d_in[15];
  const float* b1   = (const float*)d_in[16];
  const float* W2   = (const float*)d_in[17];
  const float* b2   = (const float*)d_in[18];

  char* ws = (char*)d_ws;
  const size_t MB = 1024 * 1024;
  bf16*  xb   = (bf16*)(ws + 0);        // 8 MB; reused as h_bf16 after LN1
  bf16*  Wqb  = (bf16*)(ws + 8  * MB);
  bf16*  Wkb  = (bf16*)(ws + 10 * MB);
  bf16*  Wvb  = (bf16*)(ws + 12 * MB);
  bf16*  Wob  = (bf16*)(ws + 14 * MB);
  bf16*  W1b  = (bf16*)(ws + 16 * MB);  // 8 MB
  bf16*  W2b  = (bf16*)(ws + 24 * MB);  // 8 MB
  bf16*  Qb   = (bf16*)(ws + 32 * MB);  // 8 MB
  bf16*  Kb   = (bf16*)(ws + 40 * MB);
  bf16*  Vb   = (bf16*)(ws + 48 * MB);  // natural V; dead after transpose
  bf16*  Vt   = (bf16*)(ws + 56 * MB);  // V^T [(b*16+h)*64+d][1024]
  bf16*  AOb  = (bf16*)(ws + 48 * MB);  // attention out (overwrites Vb)
  float* part = (float*)(ws + 64 * MB); // 2 x 16 MB fp32 split-K partials
  bf16*  f1   = Qb;                     // 32 MB overlay (Qb..Vt dead by FFN1)
  bf16*  hb   = xb;
  float* p0 = part;
  float* p1 = part + (size_t)4096 * 1024;

  cast_all<<<16384, 256, 0, stream>>>(x, Wq, Wk, Wv, Wo, W1, W2,
                                      xb, Wqb, Wkb, Wvb, Wob, W1b, W2b);

  gemm_qkv<<<dim3(32, 8, 3), 256, 0, stream>>>(xb, Wqb, Wkb, Wvb, bq, bk, bv, Qb, Kb, Vb, D, D);
  transpose_v<<<dim3(16, 64), 256, 0, stream>>>(Vb, Vt);
  attn_kernel<<<dim3(64, 16), 256, 0, stream>>>(Qb, Kb, Vt, Wrel, AOb);
  // AO projection: 256x128 split-K z=2 -> 256 blocks, NT=8
  gemm256x128_splitk<<<dim3(16, 8, 2), 512, 0, stream>>>(AOb, Wob, p0, p1, D, D, 512);
  ln_fuse<<<4096, 256, 0, stream>>>(p0, p1, nullptr, nullptr,
                                    bo, x, nullptr, g1, be1, nullptr, hb);
  gemm256<<<dim3(16, 16), 512, 0, stream>>>(hb, W1b, b1, f1, DFF, D, 1);
  // FFN2: 256x128 split-K z=2 -> 256 blocks, NT=32
  gemm256x128_splitk<<<dim3(16, 8, 2), 512, 0, stream>>>(f1, W2b, p0, p1, D, DFF, 2048);
  ln_fuse<<<4096, 256, 0, stream>>>(p0, p1, nullptr, nullptr,
                                    b2, nullptr, hb, g2, be2, (float*)d_out, nullptr);
}